// Round 7
// baseline (216.625 us; speedup 1.0000x reference)
//
#include <hip/hip_runtime.h>
#include <math.h>

#define N_PRED  12
#define N_DRIFT 2
#define N_DW    3
#define N_NODES 4096
#define BB      128
#define LL      16
#define BN      (BB * N_NODES)   // 524288 pairs
#define TPB     128              // 2 waves; each wave owns 64 pairs
#define NBLK    (BN / TPB)       // 4096 blocks
#define XROW    13               // float4 slots per pair row (12 data + 1 pad)
#define WROW    (64 * XROW)      // 832 float4 slots per wave region

// ---------------------------------------------------------------------------
// Pre-kernel: fold (deform ∘ conv_t) and (deform ∘ conv_n) into dense uniform
// matrices Mt, Mn of shape [48][12]. Unchanged (verified correct).
// ---------------------------------------------------------------------------
__global__ void deform_precompute(const float* __restrict__ offset_t,
                                  const float* __restrict__ offset_n,
                                  const float* __restrict__ conv_t_w,
                                  const float* __restrict__ conv_n_w,
                                  float* __restrict__ Mt,
                                  float* __restrict__ Mn) {
    int t = threadIdx.x;
    if (t >= N_PRED * N_DW * LL) return;      // 576
    int q  = t % N_PRED;
    int kl = t / N_PRED;
    int k  = kl / LL;
    int l  = kl % LL;

    auto coef = [&](const float* off, int c) -> float {
        float pos = tanhf(off[k * N_PRED + c]) * (float)N_DRIFT
                    + (float)(c + N_DRIFT);
        float idf = floorf(pos);
        float fr  = pos - idf;
        int   id  = (int)idf;
        if (l == id)     return 1.0f - fr;
        if (l == id + 1) return fr;
        return 0.0f;
    };

    float mt = 0.0f;
    #pragma unroll
    for (int h = 0; h < 3; ++h) {
        int c = q - 1 + h;
        if (c < 0 || c >= N_PRED) continue;
        mt += conv_t_w[k * 3 + h] * coef(offset_t, c);
    }

    float mn = 0.0f;
    #pragma unroll
    for (int c = 0; c < N_PRED; ++c) {
        mn += conv_n_w[q * (N_PRED * N_DW) + c * N_DW + k] * coef(offset_n, c);
    }

    Mt[kl * N_PRED + q] = mt;
    Mn[kl * N_PRED + q] = mn;
}

// ---------------------------------------------------------------------------
// Main kernel, R9 = R7 (verified, 61us) + weights moved OFF the scalar pipe.
//
// Cross-round analysis: R2/R7/R8 all saturate at ~5K cycles per chunk per CU
// regardless of occupancy (10/12/4 waves) or pipelining -> a shared per-CU
// rate limit. The one per-CU resource every chunk stresses identically: the
// SCALAR pipe -- ~300 s_loads per chunk re-streaming Mt/Mn/W (5.2 KB)
// through a 102-SGPR window, one scalar unit shared by all waves on the CU.
//
// Fix: stage Mt/Mn/W into LDS once per block (single startup __syncthreads,
// the only barrier), then read them in the FMA loop as uniform-address
// ds_read_b128 BROADCASTS (same addr across 64 lanes = free broadcast) into
// VGPR float4s; v_fma with all-VGPR operands. Weight stream now rides the
// DS pipe (~324 broadcasts/chunk, ~1K cy/chunk-CU) instead of the serialized
// scalar pipe (~5K cy/chunk-CU).
//
// Everything else is R7 verbatim: wave-private stage/compute/restage, no
// steady-state barriers, stride-13 conflict-free x transpose, ctrl/bparam
// per-thread reg loads hidden under the matvec, outputs restaged through the
// wave's own x region, all global IO 1 KB/wave/instr lane-linear.
// LDS = 26624 + 4608 + 576 = 31808 B -> 5 blocks/CU = 10 waves/CU.
// ---------------------------------------------------------------------------
#define FMA4(acc, w4, xv, o)                      \
    acc[(o)+0] = fmaf((w4).x, (xv), acc[(o)+0]); \
    acc[(o)+1] = fmaf((w4).y, (xv), acc[(o)+1]); \
    acc[(o)+2] = fmaf((w4).z, (xv), acc[(o)+2]); \
    acc[(o)+3] = fmaf((w4).w, (xv), acc[(o)+3]);

__global__ __launch_bounds__(TPB) void deform_main(
        const float* __restrict__ inp,      // (BN, 3, 16)
        const float* __restrict__ ctrl,     // (BN, 12)
        const float* __restrict__ W,        // (12, 12)
        const float* __restrict__ bparam,   // (N_NODES, 12)
        const float* __restrict__ conv_t_b, // (1,)
        const float* __restrict__ conv_n_b, // (12,)
        const float* __restrict__ Mt,       // (48, 12)
        const float* __restrict__ Mn,       // (48, 12)
        float* __restrict__ out) {          // (BN, 12)
    __shared__ float4 xs4[TPB * XROW];      // 26624 B; [w*WROW..] per wave
    __shared__ float4 wl[48 * 6];           //  4608 B; [kl]: 0..2=Mt 3..5=Mn
    __shared__ float4 wW[36];               //   576 B; gate W rows

    const int t    = threadIdx.x;
    const int l    = t & 63;                // lane
    const int w    = t >> 6;                // wave (0/1)
    const int base = w * WROW;              // wave-private LDS base (float4)

    // ---- stage weights once (cooperative; the kernel's only barrier) ----
    #pragma unroll
    for (int s = t; s < 288; s += TPB) {    // s = kl*6 + part
        int kl   = s / 6;
        int part = s - kl * 6;
        const float* src = (part < 3 ? Mt : Mn) + kl * 12 + (part % 3) * 4;
        wl[s] = *(const float4*)src;
    }
    if (t < 36) wW[t] = ((const float4*)W)[t];

    // ---- 12 coalesced 1 KB x loads (issued before the barrier; the
    //      barrier's implicit drain costs one latency, startup only) ----
    const float4* gin = (const float4*)inp + (size_t)blockIdx.x * (TPB * 12)
                        + w * 768;
    float4 pre[12];
    #pragma unroll
    for (int i = 0; i < 12; ++i) pre[i] = gin[i * 64 + l];

    __syncthreads();                        // weights visible to both waves

    // ---- stage x to stride-13 rows (wave-local transpose) ----
    #pragma unroll
    for (int i = 0; i < 12; ++i) {
        int A = i * 64 + l;                 // wave-local float4 idx 0..767
        xs4[base + (A / 12) * XROW + (A % 12)] = pre[i];
    }

    // ---- ctrl + bparam register loads; consumed at the gate (~2600 cy
    //      later) so their latency hides under the matvec ----
    const int tid = blockIdx.x * TPB + t;
    const int n   = tid & (N_NODES - 1);
    float4 cv[3], bv[3];
    {
        const float4* gct = (const float4*)ctrl + (size_t)tid * 3;
        #pragma unroll
        for (int i = 0; i < 3; ++i) cv[i] = gct[i];
        const float4* gbp = (const float4*)bparam + (size_t)n * 3;
        #pragma unroll
        for (int i = 0; i < 3; ++i) bv[i] = gbp[i];
    }

    // ---- pred_t / pred_n accumulators (biases; 4 scalar loads, trivial) ----
    float acct[12], accn[12];
    const float ctb = conv_t_b[0];
    #pragma unroll
    for (int q = 0; q < N_PRED; ++q) {
        acct[q] = ctb;
        accn[q] = conv_n_b[q];
    }

    // ---- folded matvecs: 1152 FMAs; weights via uniform-address b128
    //      LDS broadcasts (free broadcast, no bank conflict); x row from
    //      stride-13 slots (conflict-free b128) ----
    #pragma unroll
    for (int c = 0; c < 12; ++c) {
        float4 v = xs4[base + l * XROW + c];
        #pragma unroll
        for (int e = 0; e < 4; ++e) {
            float xv = (e == 0) ? v.x : (e == 1) ? v.y : (e == 2) ? v.z : v.w;
            const int kl = 4 * c + e;
            float4 a0 = wl[kl * 6 + 0];
            float4 a1 = wl[kl * 6 + 1];
            float4 a2 = wl[kl * 6 + 2];
            float4 b0 = wl[kl * 6 + 3];
            float4 b1 = wl[kl * 6 + 4];
            float4 b2 = wl[kl * 6 + 5];
            FMA4(acct, a0, xv, 0)
            FMA4(acct, a1, xv, 4)
            FMA4(acct, a2, xv, 8)
            FMA4(accn, b0, xv, 0)
            FMA4(accn, b1, xv, 4)
            FMA4(accn, b2, xv, 8)
        }
    }

    // ---- gate matvec (ctrl/bparam regs; W via LDS broadcast) ----
    float accg[12];
    const float* bvf = (const float*)bv;
    const float* cvf = (const float*)cv;
    #pragma unroll
    for (int q = 0; q < N_PRED; ++q) accg[q] = bvf[q];
    #pragma unroll
    for (int p = 0; p < N_PRED; ++p) {
        float cval = cvf[p];
        float4 w0 = wW[p * 3 + 0];
        float4 w1 = wW[p * 3 + 1];
        float4 w2 = wW[p * 3 + 2];
        FMA4(accg, w0, cval, 0)
        FMA4(accg, w1, cval, 4)
        FMA4(accg, w2, cval, 8)
    }

    // ---- sigmoid gate + blend ----
    float4 o4[3];
    float* ov = (float*)o4;
    #pragma unroll
    for (int q = 0; q < N_PRED; ++q) {
        float g = 1.0f / (1.0f + __expf(-accg[q]));
        ov[q] = accn[q] * g + acct[q] * (1.0f - g);
    }

    // ---- output restage into own wave's x region (same-wave DS in-order,
    //      no barrier needed) -> coalesced 1 KB stores ----
    #pragma unroll
    for (int j = 0; j < 3; ++j) {
        xs4[base + 3 * l + j] = o4[j];      // quads 3l+j distinct mod 8
    }
    float4* gout = (float4*)out + (size_t)blockIdx.x * (TPB * 3) + w * 192;
    #pragma unroll
    for (int j = 0; j < 3; ++j) {
        gout[j * 64 + l] = xs4[base + j * 64 + l];
    }
}

extern "C" void kernel_launch(void* const* d_in, const int* in_sizes, int n_in,
                              void* d_out, int out_size, void* d_ws, size_t ws_size,
                              hipStream_t stream) {
    const float* inp      = (const float*)d_in[0];
    const float* ctrl     = (const float*)d_in[1];
    const float* offset_t = (const float*)d_in[2];
    const float* offset_n = (const float*)d_in[3];
    const float* conv_t_w = (const float*)d_in[4];
    const float* conv_t_b = (const float*)d_in[5];
    const float* conv_n_w = (const float*)d_in[6];
    const float* conv_n_b = (const float*)d_in[7];
    const float* W        = (const float*)d_in[8];
    const float* bparam   = (const float*)d_in[9];
    float* out = (float*)d_out;

    float* Mt = (float*)d_ws;            // 576 floats
    float* Mn = Mt + N_DW * LL * N_PRED; // 576 floats (ws >= 4608 B)

    deform_precompute<<<1, 576, 0, stream>>>(offset_t, offset_n,
                                             conv_t_w, conv_n_w, Mt, Mn);
    deform_main<<<NBLK, TPB, 0, stream>>>(inp, ctrl, W, bparam,
                                          conv_t_b, conv_n_b, Mt, Mn, out);
}

// Round 10
// 201.473 us; speedup vs baseline: 1.0752x; 1.0752x over previous
//
#include <hip/hip_runtime.h>
#include <math.h>

#define N_PRED  12
#define N_DRIFT 2
#define N_DW    3
#define N_NODES 4096
#define BB      128
#define LL      16
#define BN      (BB * N_NODES)   // 524288 pairs
#define TPB     128              // 2 waves; each wave owns 64 pairs
#define NBLK    (BN / TPB)       // 4096 blocks
#define XROW    13               // float4 slots per pair row (12 data + 1 pad)
#define WROW    (64 * XROW)      // 832 float4 slots per wave region

// ---------------------------------------------------------------------------
// Pre-kernel: fold (deform ∘ conv_t) and (deform ∘ conv_n) into dense uniform
// matrices Mt, Mn of shape [48][12]. Unchanged (verified correct).
// ---------------------------------------------------------------------------
__global__ void deform_precompute(const float* __restrict__ offset_t,
                                  const float* __restrict__ offset_n,
                                  const float* __restrict__ conv_t_w,
                                  const float* __restrict__ conv_n_w,
                                  float* __restrict__ Mt,
                                  float* __restrict__ Mn) {
    int t = threadIdx.x;
    if (t >= N_PRED * N_DW * LL) return;      // 576
    int q  = t % N_PRED;
    int kl = t / N_PRED;
    int k  = kl / LL;
    int l  = kl % LL;

    auto coef = [&](const float* off, int c) -> float {
        float pos = tanhf(off[k * N_PRED + c]) * (float)N_DRIFT
                    + (float)(c + N_DRIFT);
        float idf = floorf(pos);
        float fr  = pos - idf;
        int   id  = (int)idf;
        if (l == id)     return 1.0f - fr;
        if (l == id + 1) return fr;
        return 0.0f;
    };

    float mt = 0.0f;
    #pragma unroll
    for (int h = 0; h < 3; ++h) {
        int c = q - 1 + h;
        if (c < 0 || c >= N_PRED) continue;
        mt += conv_t_w[k * 3 + h] * coef(offset_t, c);
    }

    float mn = 0.0f;
    #pragma unroll
    for (int c = 0; c < N_PRED; ++c) {
        mn += conv_n_w[q * (N_PRED * N_DW) + c * N_DW + k] * coef(offset_n, c);
    }

    Mt[kl * N_PRED + q] = mt;
    Mn[kl * N_PRED + q] = mn;
}

// ---------------------------------------------------------------------------
// Main kernel, R10c: third submission of the scalar-pipe experiment (rounds
// 8/9 died in container acquisition before compile; every feature here has
// individually run on HW: broadcast-FMA loop = R9, launch_bounds(TPB,1) =
// R5/R8, wave-private structure = R7).
//
// Experiment: R2/R7/R8 all saturate at ~5K cy per chunk per CU regardless of
// occupancy or pipelining -> shared per-CU rate limit; suspect = the scalar
// pipe (~300 s_loads/chunk re-streaming Mt/Mn/W, one scalar unit per CU).
// This kernel reads weights as uniform-address ds_read_b128 LDS broadcasts
// (free broadcast across 64 lanes) into VGPRs instead.
//
// Spill discipline (R4/R6/R9 rule: spill victim = whatever crosses a
// barrier): x staged to LDS BEFORE the weights barrier (pre[] dies into its
// ds_writes); only cv/bv (24 regs) cross. launch_bounds(TPB,1) gives the
// allocator headroom; occupancy stays LDS-bound: 31808 B -> 5 blocks/CU.
// ---------------------------------------------------------------------------
#define FMA4(acc, w4, xv, o)                      \
    acc[(o)+0] = fmaf((w4).x, (xv), acc[(o)+0]); \
    acc[(o)+1] = fmaf((w4).y, (xv), acc[(o)+1]); \
    acc[(o)+2] = fmaf((w4).z, (xv), acc[(o)+2]); \
    acc[(o)+3] = fmaf((w4).w, (xv), acc[(o)+3]);

__global__ __launch_bounds__(TPB, 1) void deform_main(
        const float* __restrict__ inp,      // (BN, 3, 16)
        const float* __restrict__ ctrl,     // (BN, 12)
        const float* __restrict__ W,        // (12, 12)
        const float* __restrict__ bparam,   // (N_NODES, 12)
        const float* __restrict__ conv_t_b, // (1,)
        const float* __restrict__ conv_n_b, // (12,)
        const float* __restrict__ Mt,       // (48, 12)
        const float* __restrict__ Mn,       // (48, 12)
        float* __restrict__ out) {          // (BN, 12)
    __shared__ float4 xs4[TPB * XROW];      // 26624 B; [w*WROW..] per wave
    __shared__ float4 wl[48 * 6];           //  4608 B; slot s=kl*6+part,
                                            //   part 0..2=Mt row, 3..5=Mn row
    __shared__ float4 wW[36];               //   576 B; gate W rows

    const int t    = threadIdx.x;
    const int l    = t & 63;                // lane
    const int w    = t >> 6;                // wave (0/1)
    const int base = w * WROW;              // wave-private LDS base (float4)

    // ---- weight loads for slots t and t+128 (all threads), t+256 (t<32);
    //      static register names only (rule-#20 safe) ----
    int s0 = t,      kl0 = s0 / 6, p0 = s0 - kl0 * 6;
    int s1 = t + 128, kl1 = s1 / 6, p1 = s1 - kl1 * 6;
    int s2 = t + 256, kl2 = s2 / 6, p2 = s2 - kl2 * 6;
    float4 w0 = *(const float4*)((p0 < 3 ? Mt : Mn) + kl0 * 12 + (p0 % 3) * 4);
    float4 w1 = *(const float4*)((p1 < 3 ? Mt : Mn) + kl1 * 12 + (p1 % 3) * 4);
    float4 w2 = make_float4(0.f, 0.f, 0.f, 0.f);
    if (t < 32)
        w2 = *(const float4*)((p2 < 3 ? Mt : Mn) + kl2 * 12 + (p2 % 3) * 4);
    float4 wWreg = make_float4(0.f, 0.f, 0.f, 0.f);
    if (t < 36) wWreg = ((const float4*)W)[t];

    // ---- 12 coalesced 1 KB x loads ----
    const float4* gin = (const float4*)inp + (size_t)blockIdx.x * (TPB * 12)
                        + w * 768;
    float4 pre[12];
    #pragma unroll
    for (int i = 0; i < 12; ++i) pre[i] = gin[i * 64 + l];

    // ---- stage x FIRST (pre dies into ds_writes pre-barrier: no spill) ----
    #pragma unroll
    for (int i = 0; i < 12; ++i) {
        int A = i * 64 + l;                 // wave-local float4 idx 0..767
        xs4[base + (A / 12) * XROW + (A % 12)] = pre[i];
    }
    // ---- stage weights (static indices) ----
    wl[t]       = w0;
    wl[t + 128] = w1;
    if (t < 32) wl[t + 256] = w2;
    if (t < 36) wW[t] = wWreg;

    // ---- ctrl + bparam register loads; consumed at the gate (~2600 cy
    //      later) so their latency hides under the matvec ----
    const int tid = blockIdx.x * TPB + t;
    const int n   = tid & (N_NODES - 1);
    float4 cv[3], bv[3];
    {
        const float4* gct = (const float4*)ctrl + (size_t)tid * 3;
        #pragma unroll
        for (int i = 0; i < 3; ++i) cv[i] = gct[i];
        const float4* gbp = (const float4*)bparam + (size_t)n * 3;
        #pragma unroll
        for (int i = 0; i < 3; ++i) bv[i] = gbp[i];
    }

    __syncthreads();                        // weights visible to both waves

    // ---- pred_t / pred_n accumulators (biases) ----
    float acct[12], accn[12];
    const float ctb = conv_t_b[0];
    #pragma unroll
    for (int q = 0; q < N_PRED; ++q) {
        acct[q] = ctb;
        accn[q] = conv_n_b[q];
    }

    // ---- folded matvecs: 1152 FMAs; weights via uniform-address b128
    //      LDS broadcasts; x row from stride-13 slots (conflict-free) ----
    #pragma unroll
    for (int c = 0; c < 12; ++c) {
        float4 v = xs4[base + l * XROW + c];
        #pragma unroll
        for (int e = 0; e < 4; ++e) {
            float xv = (e == 0) ? v.x : (e == 1) ? v.y : (e == 2) ? v.z : v.w;
            const int kl = 4 * c + e;
            float4 a0 = wl[kl * 6 + 0];
            float4 a1 = wl[kl * 6 + 1];
            float4 a2 = wl[kl * 6 + 2];
            float4 b0 = wl[kl * 6 + 3];
            float4 b1 = wl[kl * 6 + 4];
            float4 b2 = wl[kl * 6 + 5];
            FMA4(acct, a0, xv, 0)
            FMA4(acct, a1, xv, 4)
            FMA4(acct, a2, xv, 8)
            FMA4(accn, b0, xv, 0)
            FMA4(accn, b1, xv, 4)
            FMA4(accn, b2, xv, 8)
        }
    }

    // ---- gate matvec (ctrl/bparam regs; W via LDS broadcast) ----
    float accg[12];
    const float* bvf = (const float*)bv;
    const float* cvf = (const float*)cv;
    #pragma unroll
    for (int q = 0; q < N_PRED; ++q) accg[q] = bvf[q];
    #pragma unroll
    for (int p = 0; p < N_PRED; ++p) {
        float cval = cvf[p];
        float4 g0 = wW[p * 3 + 0];
        float4 g1 = wW[p * 3 + 1];
        float4 g2 = wW[p * 3 + 2];
        FMA4(accg, g0, cval, 0)
        FMA4(accg, g1, cval, 4)
        FMA4(accg, g2, cval, 8)
    }

    // ---- sigmoid gate + blend ----
    float4 o4[3];
    float* ov = (float*)o4;
    #pragma unroll
    for (int q = 0; q < N_PRED; ++q) {
        float g = 1.0f / (1.0f + __expf(-accg[q]));
        ov[q] = accn[q] * g + acct[q] * (1.0f - g);
    }

    // ---- output restage into own wave's x region (same-wave DS in-order,
    //      no barrier needed) -> coalesced 1 KB stores ----
    #pragma unroll
    for (int j = 0; j < 3; ++j) {
        xs4[base + 3 * l + j] = o4[j];      // quads 3l+j distinct mod 8
    }
    float4* gout = (float4*)out + (size_t)blockIdx.x * (TPB * 3) + w * 192;
    #pragma unroll
    for (int j = 0; j < 3; ++j) {
        gout[j * 64 + l] = xs4[base + j * 64 + l];
    }
}

extern "C" void kernel_launch(void* const* d_in, const int* in_sizes, int n_in,
                              void* d_out, int out_size, void* d_ws, size_t ws_size,
                              hipStream_t stream) {
    const float* inp      = (const float*)d_in[0];
    const float* ctrl     = (const float*)d_in[1];
    const float* offset_t = (const float*)d_in[2];
    const float* offset_n = (const float*)d_in[3];
    const float* conv_t_w = (const float*)d_in[4];
    const float* conv_t_b = (const float*)d_in[5];
    const float* conv_n_w = (const float*)d_in[6];
    const float* conv_n_b = (const float*)d_in[7];
    const float* W        = (const float*)d_in[8];
    const float* bparam   = (const float*)d_in[9];
    float* out = (float*)d_out;

    float* Mt = (float*)d_ws;            // 576 floats
    float* Mn = Mt + N_DW * LL * N_PRED; // 576 floats (ws >= 4608 B)

    deform_precompute<<<1, 576, 0, stream>>>(offset_t, offset_n,
                                             conv_t_w, conv_n_w, Mt, Mn);
    deform_main<<<NBLK, TPB, 0, stream>>>(inp, ctrl, W, bparam,
                                          conv_t_b, conv_n_b, Mt, Mn, out);
}